// Round 6
// baseline (170.034 us; speedup 1.0000x reference)
//
#include <hip/hip_runtime.h>
#include <hip/hip_cooperative_groups.h>

namespace cg = cooperative_groups;

// Problem constants (from reference): x is (B, C, H, W) fp32.
constexpr int Bn = 32;
constexpr int Cn = 256;
constexpr int Hn = 96;
constexpr int Wn = 48;
constexpr int Nn = Hn * Wn;       // 4608 spatial positions
constexpr int N4 = Nn / 4;        // 1152 float4 per (b,c) row
constexpr int TILES_F  = 36;      // fused: n4-tiles per batch (36*32 = 1152)
constexpr int UNITS    = Bn * TILES_F;   // 1152 work units
constexpr int TILES_P1 = 18;      // fallback pass1 tiles per batch
constexpr float BN_EPS = 1e-5f;

// native 4-float vector (HIP_vector_type is not accepted by the
// nontemporal builtins; identical 16B layout/alignment)
typedef float floatx4 __attribute__((ext_vector_type(4)));

// ---------------------------------------------------------------------------
// Fused cooperative kernel, grid-stride over UNITS work units.
//   Unit u -> (b = u/36, tile = u%36): 32 float4 n-positions.
//   Block = 256 threads: n4l = tid&31, cgrp = tid>>5 (8 channel-groups of 32).
//   Phase A: channel dots; theta -> ws, per-tile phi.g partial -> ws.
//   grid.sync()
//   Phase B: s[b] = sum(partials)/N (fixed-order, deterministic);
//            out = (theta*s)*a[c] + d[c] + x with non-temporal stores.
// ---------------------------------------------------------------------------
__global__ __launch_bounds__(256, 4) void fused_kernel(
    const float* __restrict__ x,
    const float* __restrict__ g_w, const float* __restrict__ g_b,
    const float* __restrict__ theta_w, const float* __restrict__ theta_b,
    const float* __restrict__ phi_w, const float* __restrict__ phi_b,
    const float* __restrict__ W_w, const float* __restrict__ W_b,
    const float* __restrict__ bn_gamma, const float* __restrict__ bn_beta,
    const float* __restrict__ bn_mean, const float* __restrict__ bn_var,
    float* __restrict__ theta_ws,    // B * N floats
    float* __restrict__ part_ws,     // B * 36 floats
    float* __restrict__ out)
{
    __shared__ float wg[Cn], wt[Cn], wp[Cn];
    __shared__ float a_sh[Cn], d_sh[Cn];
    __shared__ float4 red_g[4][32], red_t[4][32], red_p[4][32];
    __shared__ float s_sh;

    const int tid  = threadIdx.x;
    const int lane = tid & 63;
    const int wave = tid >> 6;
    const int n4l  = tid & 31;
    const int cgrp = tid >> 5;
    const int c0   = cgrp * 32;

    // stage weights + per-channel epilogue scalars (once)
    wg[tid] = g_w[tid];
    wt[tid] = theta_w[tid];
    wp[tid] = phi_w[tid];
    {
        const float inv_std = bn_gamma[tid] * rsqrtf(bn_var[tid] + BN_EPS);
        a_sh[tid] = W_w[tid] * inv_std;
        d_sh[tid] = fmaf(W_b[tid] - bn_mean[tid], inv_std, bn_beta[tid]);
    }
    __syncthreads();

    const float gb = g_b[0], tb = theta_b[0], pb = phi_b[0];

    // ---- Phase A -----------------------------------------------------------
    for (int u = blockIdx.x; u < UNITS; u += gridDim.x) {
        const int b    = u / TILES_F;
        const int tile = u - b * TILES_F;
        const int n4   = tile * 32 + n4l;

        const float4* xb = reinterpret_cast<const float4*>(x)
                         + (size_t)b * (size_t)(Cn * N4) + n4;

        float4 ag = {0.f, 0.f, 0.f, 0.f};
        float4 at = {0.f, 0.f, 0.f, 0.f};
        float4 ap = {0.f, 0.f, 0.f, 0.f};

        #pragma unroll 8
        for (int cc = 0; cc < 32; ++cc) {
            const int c = c0 + cc;
            const float4 xv = xb[(size_t)c * N4];
            const float cg = wg[c], ct = wt[c], cp = wp[c];
            ag.x = fmaf(cg, xv.x, ag.x);
            ag.y = fmaf(cg, xv.y, ag.y);
            ag.z = fmaf(cg, xv.z, ag.z);
            ag.w = fmaf(cg, xv.w, ag.w);
            at.x = fmaf(ct, xv.x, at.x);
            at.y = fmaf(ct, xv.y, at.y);
            at.z = fmaf(ct, xv.z, at.z);
            at.w = fmaf(ct, xv.w, at.w);
            ap.x = fmaf(cp, xv.x, ap.x);
            ap.y = fmaf(cp, xv.y, ap.y);
            ap.z = fmaf(cp, xv.z, ap.z);
            ap.w = fmaf(cp, xv.w, ap.w);
        }

        // combine the wave's two 32-channel halves (same n4l, cgrp^1)
        ag.x += __shfl_xor(ag.x, 32); ag.y += __shfl_xor(ag.y, 32);
        ag.z += __shfl_xor(ag.z, 32); ag.w += __shfl_xor(ag.w, 32);
        at.x += __shfl_xor(at.x, 32); at.y += __shfl_xor(at.y, 32);
        at.z += __shfl_xor(at.z, 32); at.w += __shfl_xor(at.w, 32);
        ap.x += __shfl_xor(ap.x, 32); ap.y += __shfl_xor(ap.y, 32);
        ap.z += __shfl_xor(ap.z, 32); ap.w += __shfl_xor(ap.w, 32);

        if (lane < 32) {
            red_g[wave][n4l] = ag;
            red_t[wave][n4l] = at;
            red_p[wave][n4l] = ap;
        }
        __syncthreads();

        if (wave == 0 && lane < 32) {
            float4 sg = red_g[0][n4l];
            float4 st = red_t[0][n4l];
            float4 sp = red_p[0][n4l];
            #pragma unroll
            for (int w = 1; w < 4; ++w) {
                const float4 rg = red_g[w][n4l];
                const float4 rt = red_t[w][n4l];
                const float4 rp = red_p[w][n4l];
                sg.x += rg.x; sg.y += rg.y; sg.z += rg.z; sg.w += rg.w;
                st.x += rt.x; st.y += rt.y; st.z += rt.z; st.w += rt.w;
                sp.x += rp.x; sp.y += rp.y; sp.z += rp.z; sp.w += rp.w;
            }

            float4 th;
            th.x = st.x + tb; th.y = st.y + tb;
            th.z = st.z + tb; th.w = st.w + tb;
            reinterpret_cast<float4*>(theta_ws)[(size_t)b * N4 + n4] = th;

            float p = (sg.x + gb) * (sp.x + pb)
                    + (sg.y + gb) * (sp.y + pb)
                    + (sg.z + gb) * (sp.z + pb)
                    + (sg.w + gb) * (sp.w + pb);

            #pragma unroll
            for (int off = 16; off > 0; off >>= 1)
                p += __shfl_down(p, off);

            if (n4l == 0)
                __hip_atomic_store(&part_ws[b * TILES_F + tile], p,
                                   __ATOMIC_RELEASE, __HIP_MEMORY_SCOPE_AGENT);
        }
        __syncthreads();   // protect red_* reuse next unit
    }

    // ---- grid-wide barrier -------------------------------------------------
    cg::this_grid().sync();

    // ---- Phase B -----------------------------------------------------------
    for (int u = blockIdx.x; u < UNITS; u += gridDim.x) {
        const int b    = u / TILES_F;
        const int tile = u - b * TILES_F;
        const int n4   = tile * 32 + n4l;

        if (tid < 64) {
            float p = 0.0f;
            if (tid < TILES_F)
                p = __hip_atomic_load(&part_ws[b * TILES_F + tid],
                                      __ATOMIC_ACQUIRE, __HIP_MEMORY_SCOPE_AGENT);
            #pragma unroll
            for (int off = 32; off > 0; off >>= 1)
                p += __shfl_down(p, off);
            if (tid == 0) s_sh = p * (1.0f / (float)Nn);
        }
        __syncthreads();
        const float sb = s_sh;

        const float4 th = reinterpret_cast<const float4*>(theta_ws)[(size_t)b * N4 + n4];
        const float tsx = th.x * sb, tsy = th.y * sb,
                    tsz = th.z * sb, tsw = th.w * sb;

        const float4* xb = reinterpret_cast<const float4*>(x)
                         + (size_t)b * (size_t)(Cn * N4) + n4;
        floatx4* ob = reinterpret_cast<floatx4*>(out)
                    + (size_t)b * (size_t)(Cn * N4) + n4;

        #pragma unroll 8
        for (int cc = 0; cc < 32; ++cc) {
            const int c = c0 + cc;
            const float a = a_sh[c];
            const float d = d_sh[c];
            const float4 xv = xb[(size_t)c * N4];

            floatx4 o;
            o.x = fmaf(tsx, a, d) + xv.x;
            o.y = fmaf(tsy, a, d) + xv.y;
            o.z = fmaf(tsz, a, d) + xv.z;
            o.w = fmaf(tsw, a, d) + xv.w;

            __builtin_nontemporal_store(o, &ob[(size_t)c * N4]);
        }
        __syncthreads();   // protect s_sh reuse next unit
    }
}

// ---------------------------------------------------------------------------
// Fallback path (proven, round 4: 77 µs): two kernels.
// ---------------------------------------------------------------------------
__global__ __launch_bounds__(512) void pass1_kernel(
    const float* __restrict__ x,
    const float* __restrict__ g_w, const float* __restrict__ g_b,
    const float* __restrict__ theta_w, const float* __restrict__ theta_b,
    const float* __restrict__ phi_w, const float* __restrict__ phi_b,
    float* __restrict__ theta_out,   // B * N floats
    float* __restrict__ part_out)    // B * 18 floats
{
    __shared__ float wg[Cn], wt[Cn], wp[Cn];
    __shared__ float4 red[3][8][64];

    const int tid  = threadIdx.x;
    const int lane = tid & 63;
    const int wave = tid >> 6;

    if (tid < Cn) {
        wg[tid] = g_w[tid];
        wt[tid] = theta_w[tid];
        wp[tid] = phi_w[tid];
    }
    __syncthreads();

    const int bx   = blockIdx.x;
    const int b    = bx / TILES_P1;
    const int tile = bx % TILES_P1;
    const int n4   = tile * 64 + lane;

    const float4* xb = reinterpret_cast<const float4*>(x)
                     + (size_t)b * (size_t)(Cn * N4) + n4;

    float4 ag = {0.f, 0.f, 0.f, 0.f};
    float4 at = {0.f, 0.f, 0.f, 0.f};
    float4 ap = {0.f, 0.f, 0.f, 0.f};

    const int c0 = wave * 32;
    #pragma unroll 8
    for (int cc = 0; cc < 32; ++cc) {
        const int c = c0 + cc;
        const float4 xv = xb[(size_t)c * N4];
        const float cg = wg[c], ct = wt[c], cp = wp[c];
        ag.x = fmaf(cg, xv.x, ag.x);
        ag.y = fmaf(cg, xv.y, ag.y);
        ag.z = fmaf(cg, xv.z, ag.z);
        ag.w = fmaf(cg, xv.w, ag.w);
        at.x = fmaf(ct, xv.x, at.x);
        at.y = fmaf(ct, xv.y, at.y);
        at.z = fmaf(ct, xv.z, at.z);
        at.w = fmaf(ct, xv.w, at.w);
        ap.x = fmaf(cp, xv.x, ap.x);
        ap.y = fmaf(cp, xv.y, ap.y);
        ap.z = fmaf(cp, xv.z, ap.z);
        ap.w = fmaf(cp, xv.w, ap.w);
    }

    red[0][wave][lane] = ag;
    red[1][wave][lane] = at;
    red[2][wave][lane] = ap;
    __syncthreads();

    if (wave == 0) {
        float4 sg = red[0][0][lane];
        float4 st = red[1][0][lane];
        float4 sp = red[2][0][lane];
        #pragma unroll
        for (int w = 1; w < 8; ++w) {
            const float4 rg = red[0][w][lane];
            const float4 rt = red[1][w][lane];
            const float4 rp = red[2][w][lane];
            sg.x += rg.x; sg.y += rg.y; sg.z += rg.z; sg.w += rg.w;
            st.x += rt.x; st.y += rt.y; st.z += rt.z; st.w += rt.w;
            sp.x += rp.x; sp.y += rp.y; sp.z += rp.z; sp.w += rp.w;
        }

        const float gb = g_b[0], tb = theta_b[0], pb = phi_b[0];

        float4 th;
        th.x = st.x + tb; th.y = st.y + tb; th.z = st.z + tb; th.w = st.w + tb;
        reinterpret_cast<float4*>(theta_out)[(size_t)b * N4 + n4] = th;

        float p = (sg.x + gb) * (sp.x + pb)
                + (sg.y + gb) * (sp.y + pb)
                + (sg.z + gb) * (sp.z + pb)
                + (sg.w + gb) * (sp.w + pb);

        #pragma unroll
        for (int off = 32; off > 0; off >>= 1)
            p += __shfl_down(p, off);

        if (lane == 0)
            part_out[b * TILES_P1 + tile] = p;
    }
}

__global__ __launch_bounds__(256) void pass2_kernel(
    const float* __restrict__ x,
    const float* __restrict__ theta_buf,
    const float* __restrict__ part_buf,
    const float* __restrict__ W_w, const float* __restrict__ W_b,
    const float* __restrict__ bn_gamma, const float* __restrict__ bn_beta,
    const float* __restrict__ bn_mean, const float* __restrict__ bn_var,
    float* __restrict__ out)
{
    __shared__ float s_sh;
    const int tid = threadIdx.x;
    const int b   = blockIdx.y;

    if (tid < 64) {
        float p = (tid < TILES_P1) ? part_buf[b * TILES_P1 + tid] : 0.0f;
        #pragma unroll
        for (int off = 16; off > 0; off >>= 1)
            p += __shfl_down(p, off);
        if (tid == 0) s_sh = p * (1.0f / (float)Nn);
    }
    __syncthreads();
    const float sb = s_sh;

    const int tg  = blockIdx.x * 256 + tid;
    const int c00 = tg / N4;
    const int n4  = tg - c00 * N4;

    const float4* xb = reinterpret_cast<const float4*>(x)
                     + (size_t)b * (size_t)(Cn * N4);
    floatx4*      ob = reinterpret_cast<floatx4*>(out)
                     + (size_t)b * (size_t)(Cn * N4);
    const float4  th = reinterpret_cast<const float4*>(theta_buf)[(size_t)b * N4 + n4];
    const float  tsx = th.x * sb, tsy = th.y * sb,
                 tsz = th.z * sb, tsw = th.w * sb;

    #pragma unroll
    for (int it = 0; it < Cn / 8; ++it) {
        const int c = c00 + it * 8;
        const float inv_std = bn_gamma[c] * rsqrtf(bn_var[c] + BN_EPS);
        const float a = W_w[c] * inv_std;
        const float d = fmaf(W_b[c] - bn_mean[c], inv_std, bn_beta[c]);

        const size_t idx = (size_t)c * N4 + n4;
        const float4 xv = xb[idx];

        floatx4 o;
        o.x = fmaf(tsx, a, d) + xv.x;
        o.y = fmaf(tsy, a, d) + xv.y;
        o.z = fmaf(tsz, a, d) + xv.z;
        o.w = fmaf(tsw, a, d) + xv.w;

        __builtin_nontemporal_store(o, &ob[idx]);
    }
}

extern "C" void kernel_launch(void* const* d_in, const int* in_sizes, int n_in,
                              void* d_out, int out_size, void* d_ws, size_t ws_size,
                              hipStream_t stream) {
    const float* x        = (const float*)d_in[0];
    const float* g_w      = (const float*)d_in[1];
    const float* g_b      = (const float*)d_in[2];
    const float* theta_w  = (const float*)d_in[3];
    const float* theta_b  = (const float*)d_in[4];
    const float* phi_w    = (const float*)d_in[5];
    const float* phi_b    = (const float*)d_in[6];
    const float* W_w      = (const float*)d_in[7];
    const float* W_b      = (const float*)d_in[8];
    const float* bn_gamma = (const float*)d_in[9];
    const float* bn_beta  = (const float*)d_in[10];
    const float* bn_mean  = (const float*)d_in[11];
    const float* bn_var   = (const float*)d_in[12];

    float* out = (float*)d_out;

    // Workspace layout (shared by both paths):
    //   part buffer (<= 1152 floats) at 0, theta (B*N floats) at +8 KiB
    float* part_buf  = (float*)d_ws;
    float* theta_buf = (float*)((char*)d_ws + 8192);

    // --- try fused cooperative path -----------------------------------------
    int maxB = 0;
    hipError_t qerr = hipOccupancyMaxActiveBlocksPerMultiprocessor(
        &maxB, reinterpret_cast<const void*>(fused_kernel), 256, 0);

    hipError_t lerr = hipErrorUnknown;
    if (qerr == hipSuccess && maxB > 0) {
        int nb = maxB * 256;           // 256 CUs on MI355X
        if (nb > UNITS) nb = UNITS;

        void* args[] = {
            (void*)&x,
            (void*)&g_w, (void*)&g_b,
            (void*)&theta_w, (void*)&theta_b,
            (void*)&phi_w, (void*)&phi_b,
            (void*)&W_w, (void*)&W_b,
            (void*)&bn_gamma, (void*)&bn_beta,
            (void*)&bn_mean, (void*)&bn_var,
            (void*)&theta_buf, (void*)&part_buf,
            (void*)&out,
        };

        lerr = hipLaunchCooperativeKernel(
            reinterpret_cast<const void*>(fused_kernel),
            dim3(nb), dim3(256), args, 0u, stream);

        if (lerr != hipSuccess && nb > 256) {
            // runtime's co-residency limit may be tighter than occupancy*CUs
            lerr = hipLaunchCooperativeKernel(
                reinterpret_cast<const void*>(fused_kernel),
                dim3(256), dim3(256), args, 0u, stream);
        }
    }

    // --- fallback: proven two-kernel path ------------------------------------
    if (lerr != hipSuccess) {
        pass1_kernel<<<Bn * TILES_P1, 512, 0, stream>>>(
            x, g_w, g_b, theta_w, theta_b, phi_w, phi_b, theta_buf, part_buf);

        dim3 g2(36, Bn);
        pass2_kernel<<<g2, 256, 0, stream>>>(
            x, theta_buf, part_buf, W_w, W_b,
            bn_gamma, bn_beta, bn_mean, bn_var, out);
    }
}

// Round 7
// 74.685 us; speedup vs baseline: 2.2767x; 2.2767x over previous
//
#include <hip/hip_runtime.h>

// Problem constants (from reference): x is (B, C, H, W) fp32.
constexpr int Bn = 32;
constexpr int Cn = 256;
constexpr int Hn = 96;
constexpr int Wn = 48;
constexpr int Nn = Hn * Wn;       // 4608 spatial positions
constexpr int N4 = Nn / 4;        // 1152 float4 per (b,c) row
constexpr int TILES = 72;         // 16-float4 tiles per batch (72*16 = 1152)
constexpr int NBLK  = Bn * TILES; // 2304 blocks = exactly 9 per CU
constexpr float BN_EPS = 1e-5f;

// native 4-float vector (HIP_vector_type is not accepted by the
// nontemporal builtins; identical 16B layout/alignment)
typedef float floatx4 __attribute__((ext_vector_type(4)));

// ---------------------------------------------------------------------------
// Pass 1: g/theta/phi channel dots.
//   Grid = 2304 blocks x 128 threads (2 waves) = 9 blocks/CU exactly
//   (balanced tail), 18 waves/CU.
//   Block owns (b, tile of 16 float4). Thread: pos = tid&15, grp = tid>>4;
//   grp covers channels [32*grp, 32*grp+32).
//   Reduce 8 grps: shfl_xor(16), shfl_xor(32) within each wave, then one
//   LDS add across the two waves. theta -> ws; per-tile phi.g partial -> ws
//   (deterministic fixed-order tree, no atomics).
// ---------------------------------------------------------------------------
__global__ __launch_bounds__(128, 5) void pass1_kernel(
    const float* __restrict__ x,
    const float* __restrict__ g_w, const float* __restrict__ g_b,
    const float* __restrict__ theta_w, const float* __restrict__ theta_b,
    const float* __restrict__ phi_w, const float* __restrict__ phi_b,
    float* __restrict__ theta_out,   // B * N floats
    float* __restrict__ part_out)    // B * 72 floats
{
    __shared__ float wg[Cn], wt[Cn], wp[Cn];
    __shared__ float4 xw_g[16], xw_t[16], xw_p[16];   // wave1 partials

    const int tid  = threadIdx.x;
    const int lane = tid & 63;
    const int wave = tid >> 6;
    const int pos  = tid & 15;
    const int grp  = tid >> 4;        // 0..7

    #pragma unroll
    for (int i = tid; i < Cn; i += 128) {
        wg[i] = g_w[i];
        wt[i] = theta_w[i];
        wp[i] = phi_w[i];
    }
    __syncthreads();

    const int bx   = blockIdx.x;
    const int b    = bx / TILES;
    const int tile = bx - b * TILES;
    const int n4   = tile * 16 + pos;   // 0..1151

    const float4* xb = reinterpret_cast<const float4*>(x)
                     + (size_t)b * (size_t)(Cn * N4) + n4;

    float4 ag = {0.f, 0.f, 0.f, 0.f};
    float4 at = {0.f, 0.f, 0.f, 0.f};
    float4 ap = {0.f, 0.f, 0.f, 0.f};

    const int c0 = grp * 32;
    #pragma unroll
    for (int k = 0; k < 4; ++k) {
        // batch 8 loads, then consume: keeps 8 dwordx4 in flight per thread
        float4 buf[8];
        #pragma unroll
        for (int i = 0; i < 8; ++i)
            buf[i] = xb[(size_t)(c0 + k * 8 + i) * N4];
        #pragma unroll
        for (int i = 0; i < 8; ++i) {
            const int c = c0 + k * 8 + i;
            const float cg = wg[c], ct = wt[c], cp = wp[c];
            const float4 xv = buf[i];
            ag.x = fmaf(cg, xv.x, ag.x);
            ag.y = fmaf(cg, xv.y, ag.y);
            ag.z = fmaf(cg, xv.z, ag.z);
            ag.w = fmaf(cg, xv.w, ag.w);
            at.x = fmaf(ct, xv.x, at.x);
            at.y = fmaf(ct, xv.y, at.y);
            at.z = fmaf(ct, xv.z, at.z);
            at.w = fmaf(ct, xv.w, at.w);
            ap.x = fmaf(cp, xv.x, ap.x);
            ap.y = fmaf(cp, xv.y, ap.y);
            ap.z = fmaf(cp, xv.z, ap.z);
            ap.w = fmaf(cp, xv.w, ap.w);
        }
    }

    // combine the wave's 4 grps (same pos): ^16 then ^32
    ag.x += __shfl_xor(ag.x, 16); ag.y += __shfl_xor(ag.y, 16);
    ag.z += __shfl_xor(ag.z, 16); ag.w += __shfl_xor(ag.w, 16);
    at.x += __shfl_xor(at.x, 16); at.y += __shfl_xor(at.y, 16);
    at.z += __shfl_xor(at.z, 16); at.w += __shfl_xor(at.w, 16);
    ap.x += __shfl_xor(ap.x, 16); ap.y += __shfl_xor(ap.y, 16);
    ap.z += __shfl_xor(ap.z, 16); ap.w += __shfl_xor(ap.w, 16);

    ag.x += __shfl_xor(ag.x, 32); ag.y += __shfl_xor(ag.y, 32);
    ag.z += __shfl_xor(ag.z, 32); ag.w += __shfl_xor(ag.w, 32);
    at.x += __shfl_xor(at.x, 32); at.y += __shfl_xor(at.y, 32);
    at.z += __shfl_xor(at.z, 32); at.w += __shfl_xor(at.w, 32);
    ap.x += __shfl_xor(ap.x, 32); ap.y += __shfl_xor(ap.y, 32);
    ap.z += __shfl_xor(ap.z, 32); ap.w += __shfl_xor(ap.w, 32);

    if (wave == 1 && lane < 16) {
        xw_g[pos] = ag;
        xw_t[pos] = at;
        xw_p[pos] = ap;
    }
    __syncthreads();

    if (wave == 0 && lane < 16) {
        const float4 rg = xw_g[pos];
        const float4 rt = xw_t[pos];
        const float4 rp = xw_p[pos];
        float4 sg = {ag.x + rg.x, ag.y + rg.y, ag.z + rg.z, ag.w + rg.w};
        float4 st = {at.x + rt.x, at.y + rt.y, at.z + rt.z, at.w + rt.w};
        float4 sp = {ap.x + rp.x, ap.y + rp.y, ap.z + rp.z, ap.w + rp.w};

        const float gb = g_b[0], tb = theta_b[0], pb = phi_b[0];

        float4 th;
        th.x = st.x + tb; th.y = st.y + tb; th.z = st.z + tb; th.w = st.w + tb;
        reinterpret_cast<float4*>(theta_out)[(size_t)b * N4 + n4] = th;

        float p = (sg.x + gb) * (sp.x + pb)
                + (sg.y + gb) * (sp.y + pb)
                + (sg.z + gb) * (sp.z + pb)
                + (sg.w + gb) * (sp.w + pb);

        // reduce the 16 pos lanes (fixed order, deterministic)
        p += __shfl_down(p, 8);
        p += __shfl_down(p, 4);
        p += __shfl_down(p, 2);
        p += __shfl_down(p, 1);

        if (pos == 0)
            part_out[b * TILES + tile] = p;
    }
}

// ---------------------------------------------------------------------------
// Pass 2: elementwise epilogue.
//   Grid = 2304 blocks x 128 threads = 9 blocks/CU exactly. Block order is
//   REVERSED so the first-dispatched blocks touch the x regions pass1 read
//   last (still L3-hot).
//   Per block: reduce the 72 per-tile partials of its batch -> s (fixed
//   order), then out = (theta*s)*a[c] + d[c] + x with non-temporal stores
//   (out is write-once; keep it out of the caches so x stays resident).
// ---------------------------------------------------------------------------
__global__ __launch_bounds__(128, 5) void pass2_kernel(
    const float* __restrict__ x,
    const float* __restrict__ theta_buf,
    const float* __restrict__ part_buf,
    const float* __restrict__ W_w, const float* __restrict__ W_b,
    const float* __restrict__ bn_gamma, const float* __restrict__ bn_beta,
    const float* __restrict__ bn_mean, const float* __restrict__ bn_var,
    float* __restrict__ out)
{
    __shared__ float a_sh[Cn], d_sh[Cn];
    __shared__ float s_sh;

    const int tid  = threadIdx.x;
    const int pos  = tid & 15;
    const int grp  = tid >> 4;        // 0..7

    const int bx   = (NBLK - 1) - blockIdx.x;   // reversed for L3 tail reuse
    const int b    = bx / TILES;
    const int tile = bx - b * TILES;
    const int n4   = tile * 16 + pos;

    // stage per-channel epilogue scalars
    #pragma unroll
    for (int i = tid; i < Cn; i += 128) {
        const float inv_std = bn_gamma[i] * rsqrtf(bn_var[i] + BN_EPS);
        a_sh[i] = W_w[i] * inv_std;
        d_sh[i] = fmaf(W_b[i] - bn_mean[i], inv_std, bn_beta[i]);
    }

    // s reduction (wave 0): 72 partials, fixed-order tree
    if (tid < 64) {
        float p = part_buf[b * TILES + tid];
        if (tid < TILES - 64)
            p += part_buf[b * TILES + 64 + tid];
        p += __shfl_down(p, 32);
        p += __shfl_down(p, 16);
        p += __shfl_down(p, 8);
        p += __shfl_down(p, 4);
        p += __shfl_down(p, 2);
        p += __shfl_down(p, 1);
        if (tid == 0) s_sh = p * (1.0f / (float)Nn);
    }
    __syncthreads();
    const float sb = s_sh;

    const float4 th = reinterpret_cast<const float4*>(theta_buf)[(size_t)b * N4 + n4];
    const float tsx = th.x * sb, tsy = th.y * sb,
                tsz = th.z * sb, tsw = th.w * sb;

    const float4* xb = reinterpret_cast<const float4*>(x)
                     + (size_t)b * (size_t)(Cn * N4) + n4;
    floatx4* ob = reinterpret_cast<floatx4*>(out)
                + (size_t)b * (size_t)(Cn * N4) + n4;

    const int c0 = grp * 32;
    #pragma unroll
    for (int k = 0; k < 4; ++k) {
        float4 buf[8];
        #pragma unroll
        for (int i = 0; i < 8; ++i)
            buf[i] = xb[(size_t)(c0 + k * 8 + i) * N4];
        #pragma unroll
        for (int i = 0; i < 8; ++i) {
            const int c = c0 + k * 8 + i;
            const float a = a_sh[c];
            const float d = d_sh[c];
            const float4 xv = buf[i];

            floatx4 o;
            o.x = fmaf(tsx, a, d) + xv.x;
            o.y = fmaf(tsy, a, d) + xv.y;
            o.z = fmaf(tsz, a, d) + xv.z;
            o.w = fmaf(tsw, a, d) + xv.w;

            __builtin_nontemporal_store(o, &ob[(size_t)c * N4]);
        }
    }
}

extern "C" void kernel_launch(void* const* d_in, const int* in_sizes, int n_in,
                              void* d_out, int out_size, void* d_ws, size_t ws_size,
                              hipStream_t stream) {
    const float* x        = (const float*)d_in[0];
    const float* g_w      = (const float*)d_in[1];
    const float* g_b      = (const float*)d_in[2];
    const float* theta_w  = (const float*)d_in[3];
    const float* theta_b  = (const float*)d_in[4];
    const float* phi_w    = (const float*)d_in[5];
    const float* phi_b    = (const float*)d_in[6];
    const float* W_w      = (const float*)d_in[7];
    const float* W_b      = (const float*)d_in[8];
    const float* bn_gamma = (const float*)d_in[9];
    const float* bn_beta  = (const float*)d_in[10];
    const float* bn_mean  = (const float*)d_in[11];
    const float* bn_var   = (const float*)d_in[12];

    float* out = (float*)d_out;

    // Workspace: partials (2304 floats) at 0; theta (B*N floats) at +16 KiB
    float* part_buf  = (float*)d_ws;
    float* theta_buf = (float*)((char*)d_ws + 16384);

    pass1_kernel<<<NBLK, 128, 0, stream>>>(
        x, g_w, g_b, theta_w, theta_b, phi_w, phi_b, theta_buf, part_buf);

    pass2_kernel<<<NBLK, 128, 0, stream>>>(
        x, theta_buf, part_buf, W_w, W_b,
        bn_gamma, bn_beta, bn_mean, bn_var, out);
}